// Round 2
// baseline (176.120 us; speedup 1.0000x reference)
//
#include <hip/hip_runtime.h>

#define NDIM 80
#define NB (NDIM * NDIM)   // 6400 batches; also elements per batch matrix
#define TOL 0.01f
#define MAXIT 101          // iteration 0 = prologue (v0, ev0); 1..100 = reference steps

__global__ void zero_out_kernel(float* __restrict__ out) {
    if (threadIdx.x < NDIM) out[threadIdx.x] = 0.f;
}

// One block per batch b = i*80+j. Matrix M = wr*rz + rc lives entirely in
// registers: thread t owns row r = t>>2, cols [20q, 20q+20), q = t&3.
// LDS holds only v[80], av[80], red[2]. 3 barriers per power iteration.
__global__ __launch_bounds__(320, 6) void fused_power_kernel(
    const float* __restrict__ x,
    const float* __restrict__ r_zeros,
    const float* __restrict__ r_const,
    const float* __restrict__ weights_t,
    const float* __restrict__ weights_r,
    float* __restrict__ out)
{
    __shared__ float v[NDIM];
    __shared__ float av[NDIM];
    __shared__ float red[2];
    __shared__ float sscale;

    const int t = threadIdx.x;
    const int b = blockIdx.x;
    const size_t base = (size_t)b * NB;
    const int r = t >> 2;          // row 0..79
    const int q = t & 3;           // column quarter
    const size_t off = base + (size_t)r * NDIM + q * 20;   // 16B-aligned

    // Stage this thread's 20-element row-slice of M into registers.
    float m[20];
    {
        const float4* a4 = reinterpret_cast<const float4*>(r_zeros + off);
        const float4* c4 = reinterpret_cast<const float4*>(r_const + off);
        const float4* w4 = reinterpret_cast<const float4*>(weights_r + off);
        #pragma unroll
        for (int u = 0; u < 5; ++u) {
            float4 a = a4[u], c = c4[u], w = w4[u];
            m[4*u+0] = fmaf(w.x, a.x, c.x);
            m[4*u+1] = fmaf(w.y, a.y, c.y);
            m[4*u+2] = fmaf(w.z, a.z, c.z);
            m[4*u+3] = fmaf(w.w, a.w, c.w);
        }
    }

    // Seed: av = all-ones, n2 = 80  =>  first normalize yields v0 = 1/sqrt(80).
    if (t < NDIM) av[t] = 1.0f;
    float n2 = (float)NDIM;
    float ev = 1e30f;               // never converges on the prologue iteration
    __syncthreads();

    for (int it = 0; it < MAXIT; ++it) {
        // v = av / ||av||   (av stable since last barrier; old v no longer needed)
        float inv = rsqrtf(n2);
        if (t < NDIM) v[t] = av[t] * inv;
        __syncthreads();                       // v ready

        // av = M v  (register FMAs; quad combine via shfl_xor)
        float p = 0.f;
        const int vq = q * 20;
        #pragma unroll
        for (int k = 0; k < 20; ++k) p = fmaf(m[k], v[vq + k], p);
        p += __shfl_xor(p, 1);
        p += __shfl_xor(p, 2);
        if (q == 0) av[r] = p;
        __syncthreads();                       // av ready

        // Fused dual reduction over the same av: n2' = ||av||^2, dot = v.av
        if (t < 64) {
            float a0 = av[t], v0 = v[t];
            float s2 = a0 * a0;
            float sd = v0 * a0;
            if (t < 16) {
                float a1 = av[t + 64], v1 = v[t + 64];
                s2 = fmaf(a1, a1, s2);
                sd = fmaf(v1, a1, sd);
            }
            #pragma unroll
            for (int o = 32; o > 0; o >>= 1) {
                s2 += __shfl_down(s2, o);
                sd += __shfl_down(sd, o);
            }
            if (t == 0) { red[0] = s2; red[1] = sd; }
        }
        __syncthreads();                       // red ready
        n2 = red[0];
        float evn = red[1];
        if (fabsf(ev - evn) < TOL) break;      // uniform across block
        ev = evn;
    }

    // Epilogue: scale = x[b]*wt[b]*r_const[i,j,i,i] / v[i];  out[k] += v[k]*scale
    if (t == 0) {
        int i_idx = b / NDIM;
        float tval = x[b] * weights_t[b]
                   * r_const[base + (size_t)i_idx * NDIM + i_idx];
        sscale = tval / v[i_idx];
    }
    __syncthreads();
    if (t < NDIM) atomicAdd(&out[t], v[t] * sscale);
}

extern "C" void kernel_launch(void* const* d_in, const int* in_sizes, int n_in,
                              void* d_out, int out_size, void* d_ws, size_t ws_size,
                              hipStream_t stream) {
    const float* x  = (const float*)d_in[0];   // (80,80)
    const float* rz = (const float*)d_in[1];   // (80,80,80,80)
    const float* rc = (const float*)d_in[2];   // (80,80,80,80)
    const float* wt = (const float*)d_in[3];   // (80,80)
    const float* wr = (const float*)d_in[4];   // (80,80,80,80)
    float* out = (float*)d_out;                // (80,)

    hipLaunchKernelGGL(zero_out_kernel, dim3(1), dim3(128), 0, stream, out);
    hipLaunchKernelGGL(fused_power_kernel, dim3(NB), dim3(320), 0, stream,
                       x, rz, rc, wt, wr, out);
}